// Round 6
// baseline (693.745 us; speedup 1.0000x reference)
//
#include <hip/hip_runtime.h>
#include <hip/hip_bf16.h>
#include <math.h>

#define N_NODES 100000
#define N_EDGES 1600000
#define NF 128
#define NC 40

#define SCAN_CHUNK 512
#define SCAN_BLOCKS ((N_NODES + SCAN_CHUNK - 1) / SCAN_CHUNK)  // 196

// XCD-affine scatter geometry
#define SC_GROUPS 8
#define SC_NODES_PER_G ((N_NODES + SC_GROUPS - 1) / SC_GROUPS)   // 12500
#define SC_CHUNKS 256
#define SC_CHUNK_E ((N_EDGES + SC_CHUNKS - 1) / SC_CHUNKS)       // 6250

// XCD-affine aggregate geometry: 4 feature slices (64B each) x 2 node halves
#define AG_HALF (N_NODES / 2)                 // 50000
#define AG_BLOCKS_PER_G (AG_HALF / 4)         // 12500 blocks (4 waves each)
#define AG_GRID (AG_BLOCKS_PER_G * 8)         // 100000

typedef __attribute__((ext_vector_type(8))) short short8v;   // 8 bf16 = 4 VGPRs
typedef __attribute__((ext_vector_type(4))) float f32x4;
typedef unsigned short ushort_t;

__device__ inline float bflo(unsigned v) { union { unsigned u; float f; } x; x.u = v << 16; return x.f; }
__device__ inline float bfhi(unsigned v) { union { unsigned u; float f; } x; x.u = v & 0xffff0000u; return x.f; }
__device__ inline ushort_t f2bf(float f) {
    __hip_bfloat16 h = __float2bfloat16(f);
    return __builtin_bit_cast(ushort_t, h);
}

// ---------------- CSR build ----------------

__global__ void k_degree(const int* __restrict__ dst, unsigned* __restrict__ cnt) {
    int e = blockIdx.x * 256 + threadIdx.x;
    if (e < N_EDGES) atomicAdd(&cnt[dst[e]], 1u);
}

__global__ void k_scanA(const unsigned* __restrict__ cnt, unsigned* __restrict__ bsum) {
    __shared__ unsigned red[256];
    int t = threadIdx.x;
    int i0 = blockIdx.x * SCAN_CHUNK + 2 * t;
    unsigned s = 0;
    if (i0 < N_NODES) s += cnt[i0];
    if (i0 + 1 < N_NODES) s += cnt[i0 + 1];
    red[t] = s; __syncthreads();
    for (int off = 128; off; off >>= 1) {
        if (t < off) red[t] += red[t + off];
        __syncthreads();
    }
    if (t == 0) bsum[blockIdx.x] = red[0];
}

__global__ void k_scanB(unsigned* bsum, unsigned* rowptr) {
    __shared__ unsigned tmp[256];
    int t = threadIdx.x;
    unsigned v = (t < SCAN_BLOCKS) ? bsum[t] : 0;
    tmp[t] = v; __syncthreads();
    for (int off = 1; off < 256; off <<= 1) {
        unsigned add = (t >= off) ? tmp[t - off] : 0;
        __syncthreads();
        tmp[t] += add;
        __syncthreads();
    }
    unsigned incl = tmp[t];
    if (t < SCAN_BLOCKS) bsum[t] = incl - v;   // exclusive
    if (t == 255) rowptr[N_NODES] = incl;      // total == N_EDGES
}

__global__ void k_scanC(const unsigned* __restrict__ cnt, const unsigned* __restrict__ bsum,
                        unsigned* __restrict__ rowptr) {
    __shared__ unsigned tmp[256];
    int t = threadIdx.x;
    int i0 = blockIdx.x * SCAN_CHUNK + 2 * t;
    unsigned c0 = (i0 < N_NODES) ? cnt[i0] : 0;
    unsigned c1 = (i0 + 1 < N_NODES) ? cnt[i0 + 1] : 0;
    unsigned s = c0 + c1;
    tmp[t] = s; __syncthreads();
    for (int off = 1; off < 256; off <<= 1) {
        unsigned add = (t >= off) ? tmp[t - off] : 0;
        __syncthreads();
        tmp[t] += add;
        __syncthreads();
    }
    unsigned excl = tmp[t] - s;
    unsigned bb = bsum[blockIdx.x];
    if (i0 < N_NODES) rowptr[i0] = bb + excl;
    if (i0 + 1 < N_NODES) rowptr[i0 + 1] = bb + excl + c0;
}

// XCD-affine scatter (round-robin blockIdx->XCD): group g handles dst range
// [g*12500,(g+1)*12500); its srcs/cursor write region stays in one XCD's L2.

__global__ __launch_bounds__(256) void k_scatter8(const int* __restrict__ src,
                                                  const int* __restrict__ dst,
                                                  unsigned* __restrict__ cursor,
                                                  unsigned* __restrict__ srcs) {
    const unsigned g = blockIdx.x & (SC_GROUPS - 1);
    const int chunk = blockIdx.x >> 3;
    const unsigned gbase = g * SC_NODES_PER_G;
    int e0 = chunk * SC_CHUNK_E;
    int e1 = e0 + SC_CHUNK_E; if (e1 > N_EDGES) e1 = N_EDGES;
    for (int e = e0 + (int)threadIdx.x; e < e1; e += 256) {
        int d = dst[e];
        int s = src[e];
        if ((unsigned)(d - gbase) < (unsigned)SC_NODES_PER_G) {
            unsigned p = atomicAdd(&cursor[d], 1u);
            srcs[p] = (unsigned)s;
        }
    }
}

// ---------------- dtype casts ----------------

__global__ void k_castx(const float* __restrict__ x, ushort_t* __restrict__ xb) {
    int i = blockIdx.x * 256 + threadIdx.x;          // group of 4 elems
    if (i < N_NODES * NF / 4) {
        float4 v = ((const float4*)x)[i];
        ushort4 o;
        o.x = f2bf(v.x); o.y = f2bf(v.y); o.z = f2bf(v.z); o.w = f2bf(v.w);
        ((ushort4*)xb)[i] = o;
    }
}

__global__ void k_castw(const float* __restrict__ w0, const float* __restrict__ w1,
                        const float* __restrict__ w2, const float* __restrict__ w3,
                        const float* __restrict__ w4, ushort_t* __restrict__ out) {
    int i = blockIdx.x * 256 + threadIdx.x;          // 5 * 16384 total
    if (i < 5 * 16384) {
        int m = i >> 14, j = i & 16383;
        const float* s = (m == 0) ? w0 : (m == 1) ? w1 : (m == 2) ? w2 : (m == 3) ? w3 : w4;
        out[i] = f2bf(s[j]);
    }
}

// ---------------- mean aggregation, XCD-affine feature-sliced ----------------
// blockIdx&7 -> XCD group; slice = gid&3 selects a 64B feature slice
// (32 bf16 dims), half = gid>>2 selects a 50000-node half. Each XCD's gather
// working set = 6.4MB (one slice) instead of 25.6MB -> L2-resident.
// Wave layout: 4 edge-slots x 16 lanes; each slot-gather is one 64B line.
// 8 edges per unrolled iteration; shfl_xor(16/32) reduces slots at the end.

__global__ __launch_bounds__(256) void k_aggregate_x(const ushort_t* __restrict__ h,
                                                     const unsigned* __restrict__ rowptr,
                                                     const unsigned* __restrict__ srcs,
                                                     ushort_t* __restrict__ agg) {
    const int gid = blockIdx.x & 7;
    const int slice = gid & 3;
    const int half = gid >> 2;
    const int b = blockIdx.x >> 3;                 // 0..12499
    const int wave = threadIdx.x >> 6;
    const int lane = threadIdx.x & 63;
    const int slot = lane >> 4;                    // edge slot 0..3
    const int d = lane & 15;                       // unsigned index within slice
    const int node = half * AG_HALF + b * 4 + wave;

    const unsigned beg = rowptr[node], end = rowptr[node + 1];
    const unsigned off = (unsigned)(slice * 16 + d);   // row is 64 unsigneds
    const unsigned* __restrict__ h32 = (const unsigned*)h;

    float a0 = 0.f, a1 = 0.f;
    unsigned i = beg;
    for (; i + 8 <= end; i += 8) {
        unsigned s0 = srcs[i + slot];
        unsigned s1 = srcs[i + 4 + slot];
        unsigned v0 = h32[(size_t)s0 * 64 + off];
        unsigned v1 = h32[(size_t)s1 * 64 + off];
        a0 += bflo(v0); a1 += bfhi(v0);
        a0 += bflo(v1); a1 += bfhi(v1);
    }
    if (i + 4 <= end) {
        unsigned s0 = srcs[i + slot];
        unsigned v0 = h32[(size_t)s0 * 64 + off];
        a0 += bflo(v0); a1 += bfhi(v0);
        i += 4;
    }
    if (i + slot < end) {
        unsigned s0 = srcs[i + slot];
        unsigned v0 = h32[(size_t)s0 * 64 + off];
        a0 += bflo(v0); a1 += bfhi(v0);
    }

    a0 += __shfl_xor(a0, 16, 64); a0 += __shfl_xor(a0, 32, 64);
    a1 += __shfl_xor(a1, 16, 64); a1 += __shfl_xor(a1, 32, 64);

    if (slot == 0) {
        float sc = 1.f / fmaxf((float)(end - beg), 1.f);
        unsigned o = ((unsigned)f2bf(a1 * sc) << 16) | (unsigned)f2bf(a0 * sc);
        ((unsigned*)agg)[(size_t)node * 64 + off] = o;
    }
}

// ---------------- MFMA GEMM: out = act(A1@W1.T [+ A2@W2.T] + bias), bf16 ----------------

template <int HAS2, int RELU>
__global__ __launch_bounds__(256) void k_mfma_gemm(const ushort_t* __restrict__ A1,
                                                   const ushort_t* __restrict__ W1,
                                                   const ushort_t* __restrict__ A2,
                                                   const ushort_t* __restrict__ W2,
                                                   const float* __restrict__ bias,
                                                   ushort_t* __restrict__ out, int nrows) {
    const int lane = threadIdx.x & 63;
    const int wv = threadIdx.x >> 6;
    const int r0 = blockIdx.x * 64 + wv * 16;
    const int lr = lane & 15;
    const int kg = lane >> 4;

    int arow = r0 + lr;
    if (arow >= nrows) arow = nrows - 1;   // clamp; stores are guarded

    const short8v* a1p = (const short8v*)(A1 + (size_t)arow * NF + kg * 8);
    short8v af1[4], af2[4];
#pragma unroll
    for (int ks = 0; ks < 4; ++ks) af1[ks] = a1p[ks * 4];
    if (HAS2) {
        const short8v* a2p = (const short8v*)(A2 + (size_t)arow * NF + kg * 8);
#pragma unroll
        for (int ks = 0; ks < 4; ++ks) af2[ks] = a2p[ks * 4];
    }

    f32x4 acc[8];
#pragma unroll
    for (int ct = 0; ct < 8; ++ct) acc[ct] = (f32x4){0.f, 0.f, 0.f, 0.f};

#pragma unroll
    for (int ct = 0; ct < 8; ++ct) {
        const short8v* b1p = (const short8v*)(W1 + (size_t)(ct * 16 + lr) * NF + kg * 8);
#pragma unroll
        for (int ks = 0; ks < 4; ++ks)
            acc[ct] = __builtin_amdgcn_mfma_f32_16x16x32_bf16(af1[ks], b1p[ks * 4], acc[ct], 0, 0, 0);
        if (HAS2) {
            const short8v* b2p = (const short8v*)(W2 + (size_t)(ct * 16 + lr) * NF + kg * 8);
#pragma unroll
            for (int ks = 0; ks < 4; ++ks)
                acc[ct] = __builtin_amdgcn_mfma_f32_16x16x32_bf16(af2[ks], b2p[ks * 4], acc[ct], 0, 0, 0);
        }
    }

    const int orow0 = r0 + kg * 4;
#pragma unroll
    for (int ct = 0; ct < 8; ++ct) {
        float bv = bias[ct * 16 + lr];
#pragma unroll
        for (int r = 0; r < 4; ++r) {
            int row = orow0 + r;
            if (row < nrows) {
                float v = acc[ct][r] + bv;
                if (RELU) v = fmaxf(v, 0.f);
                out[(size_t)row * NF + ct * 16 + lr] = f2bf(v);
            }
        }
    }
}

// ---------------- post-linear + log_softmax (bf16 input, f32 out) ----------------

__global__ __launch_bounds__(256) void k_post(const ushort_t* __restrict__ h,
                                              const float* __restrict__ Wp,
                                              const float* __restrict__ bp,
                                              float* __restrict__ out) {
    __shared__ float4 As[32][32];  // 32 rows x 128 floats
    const int t = threadIdx.x;
    const int c = t & 63;
    const int g = t >> 6;
    const int row0 = blockIdx.x * 32;
#pragma unroll
    for (int i = 0; i < 2; ++i) {
        int idx = t + i * 256;          // 512 chunks of 8 bf16
        int r = idx >> 4, q = idx & 15;
        int gr = row0 + r;
        if (gr >= N_NODES) gr = N_NODES - 1;
        short8v v = ((const short8v*)(h + (size_t)gr * NF))[q];
        float4 lo, hi;
        lo.x = bflo((ushort_t)v[0]); lo.y = bflo((ushort_t)v[1]);
        lo.z = bflo((ushort_t)v[2]); lo.w = bflo((ushort_t)v[3]);
        hi.x = bflo((ushort_t)v[4]); hi.y = bflo((ushort_t)v[5]);
        hi.z = bflo((ushort_t)v[6]); hi.w = bflo((ushort_t)v[7]);
        As[r][q * 2] = lo; As[r][q * 2 + 1] = hi;
    }
    __syncthreads();
    float acc[8];
    if (c < NC) {
        const float4* wp = (const float4*)(Wp + (size_t)c * NF);
        float bb = bp[c];
#pragma unroll
        for (int i = 0; i < 8; ++i) acc[i] = bb;
        for (int k4 = 0; k4 < 32; ++k4) {
            float4 wa = wp[k4];
#pragma unroll
            for (int i = 0; i < 8; ++i) {
                float4 av = As[g * 8 + i][k4];
                acc[i] += av.x * wa.x + av.y * wa.y + av.z * wa.z + av.w * wa.w;
            }
        }
    } else {
#pragma unroll
        for (int i = 0; i < 8; ++i) acc[i] = -INFINITY;
    }
#pragma unroll
    for (int i = 0; i < 8; ++i) {
        float v = acc[i];
        float m = v;
        for (int off = 32; off; off >>= 1) m = fmaxf(m, __shfl_xor(m, off, 64));
        float p = (c < NC) ? expf(v - m) : 0.f;
        float s = p;
        for (int off = 32; off; off >>= 1) s += __shfl_xor(s, off, 64);
        if (c < NC) {
            int r = row0 + g * 8 + i;
            if (r < N_NODES) out[(size_t)r * NC + c] = v - m - logf(s);
        }
    }
}

// ---------------- launch ----------------

extern "C" void kernel_launch(void* const* d_in, const int* in_sizes, int n_in,
                              void* d_out, int out_size, void* d_ws, size_t ws_size,
                              hipStream_t stream) {
    const float* x      = (const float*)d_in[0];
    const int*   ei     = (const int*)d_in[1];
    const float* W_pre  = (const float*)d_in[2];
    const float* b_pre  = (const float*)d_in[3];
    const float* Wl0    = (const float*)d_in[4];
    const float* bl0    = (const float*)d_in[5];
    const float* Wr0    = (const float*)d_in[6];
    const float* Wl1    = (const float*)d_in[7];
    const float* bl1    = (const float*)d_in[8];
    const float* Wr1    = (const float*)d_in[9];
    const float* W_post = (const float*)d_in[10];
    const float* b_post = (const float*)d_in[11];
    const int* src = ei;
    const int* dst = ei + N_EDGES;

    const size_t act_bytes = (size_t)N_NODES * NF * 2;   // 25.6 MB
    char* w = (char*)d_ws;
    ushort_t* xb   = (ushort_t*)w; w += act_bytes;
    ushort_t* h0   = (ushort_t*)w; w += act_bytes;
    ushort_t* h1   = (ushort_t*)w; w += act_bytes;
    ushort_t* aggb = (ushort_t*)w; w += act_bytes;
    ushort_t* wb   = (ushort_t*)w; w += (size_t)5 * 16384 * 2;
    unsigned* cnt    = (unsigned*)w; w += (size_t)(N_NODES + 32) * 4;
    unsigned* rowptr = (unsigned*)w; w += (size_t)(N_NODES + 32) * 4;
    unsigned* cursor = (unsigned*)w; w += (size_t)(N_NODES + 32) * 4;
    unsigned* bsum   = (unsigned*)w; w += 256 * 4;
    unsigned* srcs   = (unsigned*)w; w += (size_t)N_EDGES * 4;
    ushort_t* h2 = h0;   // reuse

    ushort_t* wb_pre = wb;
    ushort_t* wb_l0  = wb + 16384;
    ushort_t* wb_r0  = wb + 2 * 16384;
    ushort_t* wb_l1  = wb + 3 * 16384;
    ushort_t* wb_r1  = wb + 4 * 16384;

    float* outp = (float*)d_out;

    // CSR build
    hipMemsetAsync(cnt, 0, (size_t)N_NODES * 4, stream);
    k_degree<<<(N_EDGES + 255) / 256, 256, 0, stream>>>(dst, cnt);
    k_scanA<<<SCAN_BLOCKS, 256, 0, stream>>>(cnt, bsum);
    k_scanB<<<1, 256, 0, stream>>>(bsum, rowptr);
    k_scanC<<<SCAN_BLOCKS, 256, 0, stream>>>(cnt, bsum, rowptr);
    hipMemcpyAsync(cursor, rowptr, (size_t)N_NODES * 4, hipMemcpyDeviceToDevice, stream);
    k_scatter8<<<SC_GROUPS * SC_CHUNKS, 256, 0, stream>>>(src, dst, cursor, srcs);

    // casts
    k_castw<<<(5 * 16384 + 255) / 256, 256, 0, stream>>>(W_pre, Wl0, Wr0, Wl1, Wr1, wb);
    k_castx<<<(N_NODES * NF / 4 + 255) / 256, 256, 0, stream>>>(x, xb);

    const int mfma_grid = (N_NODES + 63) / 64;   // 1563
    const int post_grid = (N_NODES + 31) / 32;   // 3125

    // pre-linear
    k_mfma_gemm<0, 0><<<mfma_grid, 256, 0, stream>>>(xb, wb_pre, nullptr, nullptr, b_pre, h0, N_NODES);
    // conv0
    k_aggregate_x<<<AG_GRID, 256, 0, stream>>>(h0, rowptr, srcs, aggb);
    k_mfma_gemm<1, 1><<<mfma_grid, 256, 0, stream>>>(aggb, wb_l0, h0, wb_r0, bl0, h1, N_NODES);
    // conv1
    k_aggregate_x<<<AG_GRID, 256, 0, stream>>>(h1, rowptr, srcs, aggb);
    k_mfma_gemm<1, 1><<<mfma_grid, 256, 0, stream>>>(aggb, wb_l1, h1, wb_r1, bl1, h2, N_NODES);
    // post + log_softmax
    k_post<<<post_grid, 256, 0, stream>>>(h2, W_post, b_post, outp);
}

// Round 7
// 563.678 us; speedup vs baseline: 1.2307x; 1.2307x over previous
//
#include <hip/hip_runtime.h>
#include <hip/hip_bf16.h>
#include <math.h>

#define N_NODES 100000
#define N_EDGES 1600000
#define NF 128
#define NC 40

#define SCAN_CHUNK 512
#define SCAN_BLOCKS ((N_NODES + SCAN_CHUNK - 1) / SCAN_CHUNK)  // 196

// XCD-affine scatter geometry
#define SC_GROUPS 8
#define SC_NODES_PER_G ((N_NODES + SC_GROUPS - 1) / SC_GROUPS)   // 12500
#define SC_CHUNKS 256
#define SC_CHUNK_E ((N_EDGES + SC_CHUNKS - 1) / SC_CHUNKS)       // 6250

typedef __attribute__((ext_vector_type(8))) short short8v;   // 8 bf16 = 4 VGPRs
typedef __attribute__((ext_vector_type(4))) float f32x4;
typedef __attribute__((ext_vector_type(2))) float f32x2;
typedef unsigned short ushort_t;

__device__ inline float bflo(unsigned v) { union { unsigned u; float f; } x; x.u = v << 16; return x.f; }
__device__ inline float bfhi(unsigned v) { union { unsigned u; float f; } x; x.u = v & 0xffff0000u; return x.f; }
__device__ inline ushort_t f2bf(float f) {
    __hip_bfloat16 h = __float2bfloat16(f);
    return __builtin_bit_cast(ushort_t, h);
}
__device__ inline unsigned char f2fp8(float f) {
    int pk = __builtin_amdgcn_cvt_pk_fp8_f32(f, f, 0, false);
    return (unsigned char)(pk & 0xff);
}

// ---------------- CSR build ----------------

__global__ void k_degree(const int* __restrict__ dst, unsigned* __restrict__ cnt) {
    int e = blockIdx.x * 256 + threadIdx.x;
    if (e < N_EDGES) atomicAdd(&cnt[dst[e]], 1u);
}

__global__ void k_scanA(const unsigned* __restrict__ cnt, unsigned* __restrict__ bsum) {
    __shared__ unsigned red[256];
    int t = threadIdx.x;
    int i0 = blockIdx.x * SCAN_CHUNK + 2 * t;
    unsigned s = 0;
    if (i0 < N_NODES) s += cnt[i0];
    if (i0 + 1 < N_NODES) s += cnt[i0 + 1];
    red[t] = s; __syncthreads();
    for (int off = 128; off; off >>= 1) {
        if (t < off) red[t] += red[t + off];
        __syncthreads();
    }
    if (t == 0) bsum[blockIdx.x] = red[0];
}

__global__ void k_scanB(unsigned* bsum, unsigned* rowptr) {
    __shared__ unsigned tmp[256];
    int t = threadIdx.x;
    unsigned v = (t < SCAN_BLOCKS) ? bsum[t] : 0;
    tmp[t] = v; __syncthreads();
    for (int off = 1; off < 256; off <<= 1) {
        unsigned add = (t >= off) ? tmp[t - off] : 0;
        __syncthreads();
        tmp[t] += add;
        __syncthreads();
    }
    unsigned incl = tmp[t];
    if (t < SCAN_BLOCKS) bsum[t] = incl - v;   // exclusive
    if (t == 255) rowptr[N_NODES] = incl;      // total == N_EDGES
}

__global__ void k_scanC(const unsigned* __restrict__ cnt, const unsigned* __restrict__ bsum,
                        unsigned* __restrict__ rowptr) {
    __shared__ unsigned tmp[256];
    int t = threadIdx.x;
    int i0 = blockIdx.x * SCAN_CHUNK + 2 * t;
    unsigned c0 = (i0 < N_NODES) ? cnt[i0] : 0;
    unsigned c1 = (i0 + 1 < N_NODES) ? cnt[i0 + 1] : 0;
    unsigned s = c0 + c1;
    tmp[t] = s; __syncthreads();
    for (int off = 1; off < 256; off <<= 1) {
        unsigned add = (t >= off) ? tmp[t - off] : 0;
        __syncthreads();
        tmp[t] += add;
        __syncthreads();
    }
    unsigned excl = tmp[t] - s;
    unsigned bb = bsum[blockIdx.x];
    if (i0 < N_NODES) rowptr[i0] = bb + excl;
    if (i0 + 1 < N_NODES) rowptr[i0 + 1] = bb + excl + c0;
}

// XCD-affine scatter (round-robin blockIdx->XCD): group g handles dst range
// [g*12500,(g+1)*12500); its srcs/cursor write region stays in one XCD's L2.

__global__ __launch_bounds__(256) void k_scatter8(const int* __restrict__ src,
                                                  const int* __restrict__ dst,
                                                  unsigned* __restrict__ cursor,
                                                  unsigned* __restrict__ srcs) {
    const unsigned g = blockIdx.x & (SC_GROUPS - 1);
    const int chunk = blockIdx.x >> 3;
    const unsigned gbase = g * SC_NODES_PER_G;
    int e0 = chunk * SC_CHUNK_E;
    int e1 = e0 + SC_CHUNK_E; if (e1 > N_EDGES) e1 = N_EDGES;
    for (int e = e0 + (int)threadIdx.x; e < e1; e += 256) {
        int d = dst[e];
        int s = src[e];
        if ((unsigned)(d - gbase) < (unsigned)SC_NODES_PER_G) {
            unsigned p = atomicAdd(&cursor[d], 1u);
            srcs[p] = (unsigned)s;
        }
    }
}

// ---------------- dtype casts ----------------

__global__ void k_castx(const float* __restrict__ x, ushort_t* __restrict__ xb) {
    int i = blockIdx.x * 256 + threadIdx.x;          // group of 4 elems
    if (i < N_NODES * NF / 4) {
        float4 v = ((const float4*)x)[i];
        ushort4 o;
        o.x = f2bf(v.x); o.y = f2bf(v.y); o.z = f2bf(v.z); o.w = f2bf(v.w);
        ((ushort4*)xb)[i] = o;
    }
}

__global__ void k_castw(const float* __restrict__ w0, const float* __restrict__ w1,
                        const float* __restrict__ w2, const float* __restrict__ w3,
                        const float* __restrict__ w4, ushort_t* __restrict__ out) {
    int i = blockIdx.x * 256 + threadIdx.x;          // 5 * 16384 total
    if (i < 5 * 16384) {
        int m = i >> 14, j = i & 16383;
        const float* s = (m == 0) ? w0 : (m == 1) ? w1 : (m == 2) ? w2 : (m == 3) ? w3 : w4;
        out[i] = f2bf(s[j]);
    }
}

// ---------------- mean aggregation over fp8 shadow copy ----------------
// One wave per node (round-5 structure). Row = 128 fp8 = 32 dwords. Lanes
// 0-31 handle edge i (dword q each), lanes 32-63 edge i+1; each lane owns
// dims 4q..4q+3 in f32; shfl_xor(32) combines the two edge slots. Gather is
// 2 cache lines per edge (vs 4 for bf16) and a 12.8 MB working set.

__global__ __launch_bounds__(256) void k_aggregate8(const unsigned* __restrict__ h32,
                                                    const unsigned* __restrict__ rowptr,
                                                    const unsigned* __restrict__ srcs,
                                                    ushort_t* __restrict__ agg) {
    int wave = threadIdx.x >> 6;
    int lane = threadIdx.x & 63;
    int node = blockIdx.x * 4 + wave;
    if (node >= N_NODES) return;
    const int half = lane >> 5;
    const int q = lane & 31;
    unsigned beg = rowptr[node], end = rowptr[node + 1];
    float a0 = 0.f, a1 = 0.f, a2 = 0.f, a3 = 0.f;
    unsigned i = beg;
    for (; i + 2 <= end; i += 2) {
        unsigned s = srcs[i + half];
        unsigned v = h32[(size_t)s * 32 + q];
        f32x2 lo = __builtin_amdgcn_cvt_pk_f32_fp8((int)v, false);
        f32x2 hi = __builtin_amdgcn_cvt_pk_f32_fp8((int)v, true);
        a0 += lo.x; a1 += lo.y; a2 += hi.x; a3 += hi.y;
    }
    if (i < end && half == 0) {
        unsigned s = srcs[i];
        unsigned v = h32[(size_t)s * 32 + q];
        f32x2 lo = __builtin_amdgcn_cvt_pk_f32_fp8((int)v, false);
        f32x2 hi = __builtin_amdgcn_cvt_pk_f32_fp8((int)v, true);
        a0 += lo.x; a1 += lo.y; a2 += hi.x; a3 += hi.y;
    }
    a0 += __shfl_xor(a0, 32, 64);
    a1 += __shfl_xor(a1, 32, 64);
    a2 += __shfl_xor(a2, 32, 64);
    a3 += __shfl_xor(a3, 32, 64);
    if (half == 0) {
        float sc = 1.f / fmaxf((float)(end - beg), 1.f);
        ushort4 o;
        o.x = f2bf(a0 * sc); o.y = f2bf(a1 * sc);
        o.z = f2bf(a2 * sc); o.w = f2bf(a3 * sc);
        ((ushort4*)(agg + (size_t)node * NF))[q] = o;
    }
}

// ---------------- MFMA GEMM: out = act(A1@W1.T [+ A2@W2.T] + bias), bf16 ----------------
// W8: also write an fp8-e4m3 shadow copy (gather source for next aggregate).

template <int HAS2, int RELU, int W8>
__global__ __launch_bounds__(256) void k_mfma_gemm(const ushort_t* __restrict__ A1,
                                                   const ushort_t* __restrict__ W1,
                                                   const ushort_t* __restrict__ A2,
                                                   const ushort_t* __restrict__ W2,
                                                   const float* __restrict__ bias,
                                                   ushort_t* __restrict__ out,
                                                   unsigned char* __restrict__ out8,
                                                   int nrows) {
    const int lane = threadIdx.x & 63;
    const int wv = threadIdx.x >> 6;
    const int r0 = blockIdx.x * 64 + wv * 16;
    const int lr = lane & 15;
    const int kg = lane >> 4;

    int arow = r0 + lr;
    if (arow >= nrows) arow = nrows - 1;   // clamp; stores are guarded

    const short8v* a1p = (const short8v*)(A1 + (size_t)arow * NF + kg * 8);
    short8v af1[4], af2[4];
#pragma unroll
    for (int ks = 0; ks < 4; ++ks) af1[ks] = a1p[ks * 4];
    if (HAS2) {
        const short8v* a2p = (const short8v*)(A2 + (size_t)arow * NF + kg * 8);
#pragma unroll
        for (int ks = 0; ks < 4; ++ks) af2[ks] = a2p[ks * 4];
    }

    f32x4 acc[8];
#pragma unroll
    for (int ct = 0; ct < 8; ++ct) acc[ct] = (f32x4){0.f, 0.f, 0.f, 0.f};

#pragma unroll
    for (int ct = 0; ct < 8; ++ct) {
        const short8v* b1p = (const short8v*)(W1 + (size_t)(ct * 16 + lr) * NF + kg * 8);
#pragma unroll
        for (int ks = 0; ks < 4; ++ks)
            acc[ct] = __builtin_amdgcn_mfma_f32_16x16x32_bf16(af1[ks], b1p[ks * 4], acc[ct], 0, 0, 0);
        if (HAS2) {
            const short8v* b2p = (const short8v*)(W2 + (size_t)(ct * 16 + lr) * NF + kg * 8);
#pragma unroll
            for (int ks = 0; ks < 4; ++ks)
                acc[ct] = __builtin_amdgcn_mfma_f32_16x16x32_bf16(af2[ks], b2p[ks * 4], acc[ct], 0, 0, 0);
        }
    }

    const int orow0 = r0 + kg * 4;
#pragma unroll
    for (int ct = 0; ct < 8; ++ct) {
        float bv = bias[ct * 16 + lr];
#pragma unroll
        for (int r = 0; r < 4; ++r) {
            int row = orow0 + r;
            if (row < nrows) {
                float v = acc[ct][r] + bv;
                if (RELU) v = fmaxf(v, 0.f);
                out[(size_t)row * NF + ct * 16 + lr] = f2bf(v);
                if (W8) out8[(size_t)row * NF + ct * 16 + lr] = f2fp8(v);
            }
        }
    }
}

// ---------------- post-linear + log_softmax (bf16 input, f32 out) ----------------

__global__ __launch_bounds__(256) void k_post(const ushort_t* __restrict__ h,
                                              const float* __restrict__ Wp,
                                              const float* __restrict__ bp,
                                              float* __restrict__ out) {
    __shared__ float4 As[32][32];  // 32 rows x 128 floats
    const int t = threadIdx.x;
    const int c = t & 63;
    const int g = t >> 6;
    const int row0 = blockIdx.x * 32;
#pragma unroll
    for (int i = 0; i < 2; ++i) {
        int idx = t + i * 256;          // 512 chunks of 8 bf16
        int r = idx >> 4, q = idx & 15;
        int gr = row0 + r;
        if (gr >= N_NODES) gr = N_NODES - 1;
        short8v v = ((const short8v*)(h + (size_t)gr * NF))[q];
        float4 lo, hi;
        lo.x = bflo((ushort_t)v[0]); lo.y = bflo((ushort_t)v[1]);
        lo.z = bflo((ushort_t)v[2]); lo.w = bflo((ushort_t)v[3]);
        hi.x = bflo((ushort_t)v[4]); hi.y = bflo((ushort_t)v[5]);
        hi.z = bflo((ushort_t)v[6]); hi.w = bflo((ushort_t)v[7]);
        As[r][q * 2] = lo; As[r][q * 2 + 1] = hi;
    }
    __syncthreads();
    float acc[8];
    if (c < NC) {
        const float4* wp = (const float4*)(Wp + (size_t)c * NF);
        float bb = bp[c];
#pragma unroll
        for (int i = 0; i < 8; ++i) acc[i] = bb;
        for (int k4 = 0; k4 < 32; ++k4) {
            float4 wa = wp[k4];
#pragma unroll
            for (int i = 0; i < 8; ++i) {
                float4 av = As[g * 8 + i][k4];
                acc[i] += av.x * wa.x + av.y * wa.y + av.z * wa.z + av.w * wa.w;
            }
        }
    } else {
#pragma unroll
        for (int i = 0; i < 8; ++i) acc[i] = -INFINITY;
    }
#pragma unroll
    for (int i = 0; i < 8; ++i) {
        float v = acc[i];
        float m = v;
        for (int off = 32; off; off >>= 1) m = fmaxf(m, __shfl_xor(m, off, 64));
        float p = (c < NC) ? expf(v - m) : 0.f;
        float s = p;
        for (int off = 32; off; off >>= 1) s += __shfl_xor(s, off, 64);
        if (c < NC) {
            int r = row0 + g * 8 + i;
            if (r < N_NODES) out[(size_t)r * NC + c] = v - m - logf(s);
        }
    }
}

// ---------------- launch ----------------

extern "C" void kernel_launch(void* const* d_in, const int* in_sizes, int n_in,
                              void* d_out, int out_size, void* d_ws, size_t ws_size,
                              hipStream_t stream) {
    const float* x      = (const float*)d_in[0];
    const int*   ei     = (const int*)d_in[1];
    const float* W_pre  = (const float*)d_in[2];
    const float* b_pre  = (const float*)d_in[3];
    const float* Wl0    = (const float*)d_in[4];
    const float* bl0    = (const float*)d_in[5];
    const float* Wr0    = (const float*)d_in[6];
    const float* Wl1    = (const float*)d_in[7];
    const float* bl1    = (const float*)d_in[8];
    const float* Wr1    = (const float*)d_in[9];
    const float* W_post = (const float*)d_in[10];
    const float* b_post = (const float*)d_in[11];
    const int* src = ei;
    const int* dst = ei + N_EDGES;

    const size_t act_bytes = (size_t)N_NODES * NF * 2;   // 25.6 MB
    const size_t act8_bytes = (size_t)N_NODES * NF;      // 12.8 MB
    char* w = (char*)d_ws;
    ushort_t* xb   = (ushort_t*)w; w += act_bytes;
    ushort_t* h0   = (ushort_t*)w; w += act_bytes;
    ushort_t* h1   = (ushort_t*)w; w += act_bytes;
    ushort_t* aggb = (ushort_t*)w; w += act_bytes;
    unsigned char* h0f8 = (unsigned char*)w; w += act8_bytes;
    unsigned char* h1f8 = (unsigned char*)w; w += act8_bytes;
    ushort_t* wb   = (ushort_t*)w; w += (size_t)5 * 16384 * 2;
    unsigned* cnt    = (unsigned*)w; w += (size_t)(N_NODES + 32) * 4;
    unsigned* rowptr = (unsigned*)w; w += (size_t)(N_NODES + 32) * 4;
    unsigned* cursor = (unsigned*)w; w += (size_t)(N_NODES + 32) * 4;
    unsigned* bsum   = (unsigned*)w; w += 256 * 4;
    unsigned* srcs   = (unsigned*)w; w += (size_t)N_EDGES * 4;
    ushort_t* h2 = h0;   // reuse

    ushort_t* wb_pre = wb;
    ushort_t* wb_l0  = wb + 16384;
    ushort_t* wb_r0  = wb + 2 * 16384;
    ushort_t* wb_l1  = wb + 3 * 16384;
    ushort_t* wb_r1  = wb + 4 * 16384;

    float* outp = (float*)d_out;

    // CSR build
    hipMemsetAsync(cnt, 0, (size_t)N_NODES * 4, stream);
    k_degree<<<(N_EDGES + 255) / 256, 256, 0, stream>>>(dst, cnt);
    k_scanA<<<SCAN_BLOCKS, 256, 0, stream>>>(cnt, bsum);
    k_scanB<<<1, 256, 0, stream>>>(bsum, rowptr);
    k_scanC<<<SCAN_BLOCKS, 256, 0, stream>>>(cnt, bsum, rowptr);
    hipMemcpyAsync(cursor, rowptr, (size_t)N_NODES * 4, hipMemcpyDeviceToDevice, stream);
    k_scatter8<<<SC_GROUPS * SC_CHUNKS, 256, 0, stream>>>(src, dst, cursor, srcs);

    // casts
    k_castw<<<(5 * 16384 + 255) / 256, 256, 0, stream>>>(W_pre, Wl0, Wr0, Wl1, Wr1, wb);
    k_castx<<<(N_NODES * NF / 4 + 255) / 256, 256, 0, stream>>>(x, xb);

    const int mfma_grid = (N_NODES + 63) / 64;   // 1563
    const int post_grid = (N_NODES + 31) / 32;   // 3125
    const int node_grid = (N_NODES + 3) / 4;     // 25000

    // pre-linear (bf16 h0 + fp8 shadow)
    k_mfma_gemm<0, 0, 1><<<mfma_grid, 256, 0, stream>>>(xb, wb_pre, nullptr, nullptr, b_pre, h0, h0f8, N_NODES);
    // conv0
    k_aggregate8<<<node_grid, 256, 0, stream>>>((const unsigned*)h0f8, rowptr, srcs, aggb);
    k_mfma_gemm<1, 1, 1><<<mfma_grid, 256, 0, stream>>>(aggb, wb_l0, h0, wb_r0, bl0, h1, h1f8, N_NODES);
    // conv1
    k_aggregate8<<<node_grid, 256, 0, stream>>>((const unsigned*)h1f8, rowptr, srcs, aggb);
    k_mfma_gemm<1, 1, 0><<<mfma_grid, 256, 0, stream>>>(aggb, wb_l1, h1, wb_r1, bl1, h2, nullptr, N_NODES);
    // post + log_softmax
    k_post<<<post_grid, 256, 0, stream>>>(h2, W_post, b_post, outp);
}

// Round 8
// 484.865 us; speedup vs baseline: 1.4308x; 1.1625x over previous
//
#include <hip/hip_runtime.h>
#include <hip/hip_bf16.h>
#include <math.h>

#define N_NODES 100000
#define N_EDGES 1600000
#define NF 128
#define NC 40

#define SCAN_CHUNK 512
#define SCAN_BLOCKS ((N_NODES + SCAN_CHUNK - 1) / SCAN_CHUNK)  // 196

// XCD-affine scatter geometry
#define SC_GROUPS 8
#define SC_NODES_PER_G ((N_NODES + SC_GROUPS - 1) / SC_GROUPS)   // 12500
#define SC_CHUNKS 256
#define SC_CHUNK_E ((N_EDGES + SC_CHUNKS - 1) / SC_CHUNKS)       // 6250

typedef __attribute__((ext_vector_type(8))) short short8v;   // 8 bf16 = 4 VGPRs
typedef __attribute__((ext_vector_type(4))) float f32x4;
typedef __attribute__((ext_vector_type(2))) float f32x2;
typedef unsigned short ushort_t;

__device__ inline float bflo(unsigned v) { union { unsigned u; float f; } x; x.u = v << 16; return x.f; }
__device__ inline float bfhi(unsigned v) { union { unsigned u; float f; } x; x.u = v & 0xffff0000u; return x.f; }
__device__ inline ushort_t f2bf(float f) {
    __hip_bfloat16 h = __float2bfloat16(f);
    return __builtin_bit_cast(ushort_t, h);
}
__device__ inline unsigned char f2fp8(float f) {
    int pk = __builtin_amdgcn_cvt_pk_fp8_f32(f, f, 0, false);
    return (unsigned char)(pk & 0xff);
}

// decode 8 fp8 (uint2) -> accumulate into a[0..7]
__device__ inline void acc_fp8x8(uint2 v, float (&a)[8]) {
    f32x2 p;
    p = __builtin_amdgcn_cvt_pk_f32_fp8((int)v.x, false); a[0] += p.x; a[1] += p.y;
    p = __builtin_amdgcn_cvt_pk_f32_fp8((int)v.x, true);  a[2] += p.x; a[3] += p.y;
    p = __builtin_amdgcn_cvt_pk_f32_fp8((int)v.y, false); a[4] += p.x; a[5] += p.y;
    p = __builtin_amdgcn_cvt_pk_f32_fp8((int)v.y, true);  a[6] += p.x; a[7] += p.y;
}

// ---------------- CSR build ----------------

__global__ void k_degree(const int* __restrict__ dst, unsigned* __restrict__ cnt) {
    int e = blockIdx.x * 256 + threadIdx.x;
    if (e < N_EDGES) atomicAdd(&cnt[dst[e]], 1u);
}

__global__ void k_scanA(const unsigned* __restrict__ cnt, unsigned* __restrict__ bsum) {
    __shared__ unsigned red[256];
    int t = threadIdx.x;
    int i0 = blockIdx.x * SCAN_CHUNK + 2 * t;
    unsigned s = 0;
    if (i0 < N_NODES) s += cnt[i0];
    if (i0 + 1 < N_NODES) s += cnt[i0 + 1];
    red[t] = s; __syncthreads();
    for (int off = 128; off; off >>= 1) {
        if (t < off) red[t] += red[t + off];
        __syncthreads();
    }
    if (t == 0) bsum[blockIdx.x] = red[0];
}

__global__ void k_scanB(unsigned* bsum, unsigned* rowptr) {
    __shared__ unsigned tmp[256];
    int t = threadIdx.x;
    unsigned v = (t < SCAN_BLOCKS) ? bsum[t] : 0;
    tmp[t] = v; __syncthreads();
    for (int off = 1; off < 256; off <<= 1) {
        unsigned add = (t >= off) ? tmp[t - off] : 0;
        __syncthreads();
        tmp[t] += add;
        __syncthreads();
    }
    unsigned incl = tmp[t];
    if (t < SCAN_BLOCKS) bsum[t] = incl - v;   // exclusive
    if (t == 255) rowptr[N_NODES] = incl;      // total == N_EDGES
}

__global__ void k_scanC(const unsigned* __restrict__ cnt, const unsigned* __restrict__ bsum,
                        unsigned* __restrict__ rowptr) {
    __shared__ unsigned tmp[256];
    int t = threadIdx.x;
    int i0 = blockIdx.x * SCAN_CHUNK + 2 * t;
    unsigned c0 = (i0 < N_NODES) ? cnt[i0] : 0;
    unsigned c1 = (i0 + 1 < N_NODES) ? cnt[i0 + 1] : 0;
    unsigned s = c0 + c1;
    tmp[t] = s; __syncthreads();
    for (int off = 1; off < 256; off <<= 1) {
        unsigned add = (t >= off) ? tmp[t - off] : 0;
        __syncthreads();
        tmp[t] += add;
        __syncthreads();
    }
    unsigned excl = tmp[t] - s;
    unsigned bb = bsum[blockIdx.x];
    if (i0 < N_NODES) rowptr[i0] = bb + excl;
    if (i0 + 1 < N_NODES) rowptr[i0 + 1] = bb + excl + c0;
}

// XCD-affine scatter (round-robin blockIdx->XCD): group g handles dst range
// [g*12500,(g+1)*12500); its srcs/cursor write region stays in one XCD's L2.

__global__ __launch_bounds__(256) void k_scatter8(const int* __restrict__ src,
                                                  const int* __restrict__ dst,
                                                  unsigned* __restrict__ cursor,
                                                  unsigned* __restrict__ srcs) {
    const unsigned g = blockIdx.x & (SC_GROUPS - 1);
    const int chunk = blockIdx.x >> 3;
    const unsigned gbase = g * SC_NODES_PER_G;
    int e0 = chunk * SC_CHUNK_E;
    int e1 = e0 + SC_CHUNK_E; if (e1 > N_EDGES) e1 = N_EDGES;
    for (int e = e0 + (int)threadIdx.x; e < e1; e += 256) {
        int d = dst[e];
        int s = src[e];
        if ((unsigned)(d - gbase) < (unsigned)SC_NODES_PER_G) {
            unsigned p = atomicAdd(&cursor[d], 1u);
            srcs[p] = (unsigned)s;
        }
    }
}

// ---------------- dtype casts ----------------

__global__ void k_castx(const float* __restrict__ x, ushort_t* __restrict__ xb) {
    int i = blockIdx.x * 256 + threadIdx.x;          // group of 4 elems
    if (i < N_NODES * NF / 4) {
        float4 v = ((const float4*)x)[i];
        ushort4 o;
        o.x = f2bf(v.x); o.y = f2bf(v.y); o.z = f2bf(v.z); o.w = f2bf(v.w);
        ((ushort4*)xb)[i] = o;
    }
}

__global__ void k_castw(const float* __restrict__ w0, const float* __restrict__ w1,
                        const float* __restrict__ w2, const float* __restrict__ w3,
                        const float* __restrict__ w4, ushort_t* __restrict__ out) {
    int i = blockIdx.x * 256 + threadIdx.x;          // 5 * 16384 total
    if (i < 5 * 16384) {
        int m = i >> 14, j = i & 16383;
        const float* s = (m == 0) ? w0 : (m == 1) ? w1 : (m == 2) ? w2 : (m == 3) ? w3 : w4;
        out[i] = f2bf(s[j]);
    }
}

// ---------------- mean aggregation over fp8 shadow copy, 4-slot MLP ----------------
// One wave per node. 4 edge-slots x 16 lanes; lane (slot,d) reads uint2 =
// 8 fp8 dims of edge (i+slot)'s source row. Unroll x2 -> 8 edges / 2
// independent gathers in flight per iteration (latency-bound fix: MLP 4x).
// shfl_xor(16/32) reduces slots; slot 0 writes the bf16 row as uint4.

__global__ __launch_bounds__(256) void k_aggregate8(const uint2* __restrict__ h64,
                                                    const unsigned* __restrict__ rowptr,
                                                    const unsigned* __restrict__ srcs,
                                                    ushort_t* __restrict__ agg) {
    int wave = threadIdx.x >> 6;
    int lane = threadIdx.x & 63;
    int node = blockIdx.x * 4 + wave;
    if (node >= N_NODES) return;
    const int slot = lane >> 4;
    const int d = lane & 15;
    unsigned beg = rowptr[node], end = rowptr[node + 1];
    float a[8];
#pragma unroll
    for (int j = 0; j < 8; ++j) a[j] = 0.f;
    unsigned i = beg;
    for (; i + 8 <= end; i += 8) {
        unsigned s0 = srcs[i + slot];
        unsigned s1 = srcs[i + 4 + slot];
        uint2 v0 = h64[(size_t)s0 * 16 + d];
        uint2 v1 = h64[(size_t)s1 * 16 + d];
        acc_fp8x8(v0, a);
        acc_fp8x8(v1, a);
    }
    if (i + 4 <= end) {
        unsigned s0 = srcs[i + slot];
        uint2 v0 = h64[(size_t)s0 * 16 + d];
        acc_fp8x8(v0, a);
        i += 4;
    }
    if (i + slot < end) {
        unsigned s0 = srcs[i + slot];
        uint2 v0 = h64[(size_t)s0 * 16 + d];
        acc_fp8x8(v0, a);
    }
#pragma unroll
    for (int j = 0; j < 8; ++j) {
        a[j] += __shfl_xor(a[j], 16, 64);
        a[j] += __shfl_xor(a[j], 32, 64);
    }
    if (slot == 0) {
        float sc = 1.f / fmaxf((float)(end - beg), 1.f);
        uint4 o;
        o.x = ((unsigned)f2bf(a[1] * sc) << 16) | (unsigned)f2bf(a[0] * sc);
        o.y = ((unsigned)f2bf(a[3] * sc) << 16) | (unsigned)f2bf(a[2] * sc);
        o.z = ((unsigned)f2bf(a[5] * sc) << 16) | (unsigned)f2bf(a[4] * sc);
        o.w = ((unsigned)f2bf(a[7] * sc) << 16) | (unsigned)f2bf(a[6] * sc);
        ((uint4*)(agg + (size_t)node * NF))[d] = o;
    }
}

// ---------------- MFMA GEMM: out = act(A1@W1.T [+ A2@W2.T] + bias), bf16 ----------------
// W8: also write an fp8-e4m3 shadow copy (gather source for next aggregate).

template <int HAS2, int RELU, int W8>
__global__ __launch_bounds__(256) void k_mfma_gemm(const ushort_t* __restrict__ A1,
                                                   const ushort_t* __restrict__ W1,
                                                   const ushort_t* __restrict__ A2,
                                                   const ushort_t* __restrict__ W2,
                                                   const float* __restrict__ bias,
                                                   ushort_t* __restrict__ out,
                                                   unsigned char* __restrict__ out8,
                                                   int nrows) {
    const int lane = threadIdx.x & 63;
    const int wv = threadIdx.x >> 6;
    const int r0 = blockIdx.x * 64 + wv * 16;
    const int lr = lane & 15;
    const int kg = lane >> 4;

    int arow = r0 + lr;
    if (arow >= nrows) arow = nrows - 1;   // clamp; stores are guarded

    const short8v* a1p = (const short8v*)(A1 + (size_t)arow * NF + kg * 8);
    short8v af1[4], af2[4];
#pragma unroll
    for (int ks = 0; ks < 4; ++ks) af1[ks] = a1p[ks * 4];
    if (HAS2) {
        const short8v* a2p = (const short8v*)(A2 + (size_t)arow * NF + kg * 8);
#pragma unroll
        for (int ks = 0; ks < 4; ++ks) af2[ks] = a2p[ks * 4];
    }

    f32x4 acc[8];
#pragma unroll
    for (int ct = 0; ct < 8; ++ct) acc[ct] = (f32x4){0.f, 0.f, 0.f, 0.f};

#pragma unroll
    for (int ct = 0; ct < 8; ++ct) {
        const short8v* b1p = (const short8v*)(W1 + (size_t)(ct * 16 + lr) * NF + kg * 8);
#pragma unroll
        for (int ks = 0; ks < 4; ++ks)
            acc[ct] = __builtin_amdgcn_mfma_f32_16x16x32_bf16(af1[ks], b1p[ks * 4], acc[ct], 0, 0, 0);
        if (HAS2) {
            const short8v* b2p = (const short8v*)(W2 + (size_t)(ct * 16 + lr) * NF + kg * 8);
#pragma unroll
            for (int ks = 0; ks < 4; ++ks)
                acc[ct] = __builtin_amdgcn_mfma_f32_16x16x32_bf16(af2[ks], b2p[ks * 4], acc[ct], 0, 0, 0);
        }
    }

    const int orow0 = r0 + kg * 4;
#pragma unroll
    for (int ct = 0; ct < 8; ++ct) {
        float bv = bias[ct * 16 + lr];
#pragma unroll
        for (int r = 0; r < 4; ++r) {
            int row = orow0 + r;
            if (row < nrows) {
                float v = acc[ct][r] + bv;
                if (RELU) v = fmaxf(v, 0.f);
                out[(size_t)row * NF + ct * 16 + lr] = f2bf(v);
                if (W8) out8[(size_t)row * NF + ct * 16 + lr] = f2fp8(v);
            }
        }
    }
}

// ---------------- post-linear + log_softmax (bf16 input, f32 out) ----------------

__global__ __launch_bounds__(256) void k_post(const ushort_t* __restrict__ h,
                                              const float* __restrict__ Wp,
                                              const float* __restrict__ bp,
                                              float* __restrict__ out) {
    __shared__ float4 As[32][32];  // 32 rows x 128 floats
    const int t = threadIdx.x;
    const int c = t & 63;
    const int g = t >> 6;
    const int row0 = blockIdx.x * 32;
#pragma unroll
    for (int i = 0; i < 2; ++i) {
        int idx = t + i * 256;          // 512 chunks of 8 bf16
        int r = idx >> 4, q = idx & 15;
        int gr = row0 + r;
        if (gr >= N_NODES) gr = N_NODES - 1;
        short8v v = ((const short8v*)(h + (size_t)gr * NF))[q];
        float4 lo, hi;
        lo.x = bflo((ushort_t)v[0]); lo.y = bflo((ushort_t)v[1]);
        lo.z = bflo((ushort_t)v[2]); lo.w = bflo((ushort_t)v[3]);
        hi.x = bflo((ushort_t)v[4]); hi.y = bflo((ushort_t)v[5]);
        hi.z = bflo((ushort_t)v[6]); hi.w = bflo((ushort_t)v[7]);
        As[r][q * 2] = lo; As[r][q * 2 + 1] = hi;
    }
    __syncthreads();
    float acc[8];
    if (c < NC) {
        const float4* wp = (const float4*)(Wp + (size_t)c * NF);
        float bb = bp[c];
#pragma unroll
        for (int i = 0; i < 8; ++i) acc[i] = bb;
        for (int k4 = 0; k4 < 32; ++k4) {
            float4 wa = wp[k4];
#pragma unroll
            for (int i = 0; i < 8; ++i) {
                float4 av = As[g * 8 + i][k4];
                acc[i] += av.x * wa.x + av.y * wa.y + av.z * wa.z + av.w * wa.w;
            }
        }
    } else {
#pragma unroll
        for (int i = 0; i < 8; ++i) acc[i] = -INFINITY;
    }
#pragma unroll
    for (int i = 0; i < 8; ++i) {
        float v = acc[i];
        float m = v;
        for (int off = 32; off; off >>= 1) m = fmaxf(m, __shfl_xor(m, off, 64));
        float p = (c < NC) ? expf(v - m) : 0.f;
        float s = p;
        for (int off = 32; off; off >>= 1) s += __shfl_xor(s, off, 64);
        if (c < NC) {
            int r = row0 + g * 8 + i;
            if (r < N_NODES) out[(size_t)r * NC + c] = v - m - logf(s);
        }
    }
}

// ---------------- launch ----------------

extern "C" void kernel_launch(void* const* d_in, const int* in_sizes, int n_in,
                              void* d_out, int out_size, void* d_ws, size_t ws_size,
                              hipStream_t stream) {
    const float* x      = (const float*)d_in[0];
    const int*   ei     = (const int*)d_in[1];
    const float* W_pre  = (const float*)d_in[2];
    const float* b_pre  = (const float*)d_in[3];
    const float* Wl0    = (const float*)d_in[4];
    const float* bl0    = (const float*)d_in[5];
    const float* Wr0    = (const float*)d_in[6];
    const float* Wl1    = (const float*)d_in[7];
    const float* bl1    = (const float*)d_in[8];
    const float* Wr1    = (const float*)d_in[9];
    const float* W_post = (const float*)d_in[10];
    const float* b_post = (const float*)d_in[11];
    const int* src = ei;
    const int* dst = ei + N_EDGES;

    const size_t act_bytes = (size_t)N_NODES * NF * 2;   // 25.6 MB
    const size_t act8_bytes = (size_t)N_NODES * NF;      // 12.8 MB
    char* w = (char*)d_ws;
    ushort_t* xb   = (ushort_t*)w; w += act_bytes;
    ushort_t* h0   = (ushort_t*)w; w += act_bytes;
    ushort_t* h1   = (ushort_t*)w; w += act_bytes;
    ushort_t* aggb = (ushort_t*)w; w += act_bytes;
    unsigned char* h0f8 = (unsigned char*)w; w += act8_bytes;
    unsigned char* h1f8 = (unsigned char*)w; w += act8_bytes;
    ushort_t* wb   = (ushort_t*)w; w += (size_t)5 * 16384 * 2;
    unsigned* cnt    = (unsigned*)w; w += (size_t)(N_NODES + 32) * 4;
    unsigned* rowptr = (unsigned*)w; w += (size_t)(N_NODES + 32) * 4;
    unsigned* cursor = (unsigned*)w; w += (size_t)(N_NODES + 32) * 4;
    unsigned* bsum   = (unsigned*)w; w += 256 * 4;
    unsigned* srcs   = (unsigned*)w; w += (size_t)N_EDGES * 4;
    ushort_t* h2 = h0;   // reuse

    ushort_t* wb_pre = wb;
    ushort_t* wb_l0  = wb + 16384;
    ushort_t* wb_r0  = wb + 2 * 16384;
    ushort_t* wb_l1  = wb + 3 * 16384;
    ushort_t* wb_r1  = wb + 4 * 16384;

    float* outp = (float*)d_out;

    // CSR build
    hipMemsetAsync(cnt, 0, (size_t)N_NODES * 4, stream);
    k_degree<<<(N_EDGES + 255) / 256, 256, 0, stream>>>(dst, cnt);
    k_scanA<<<SCAN_BLOCKS, 256, 0, stream>>>(cnt, bsum);
    k_scanB<<<1, 256, 0, stream>>>(bsum, rowptr);
    k_scanC<<<SCAN_BLOCKS, 256, 0, stream>>>(cnt, bsum, rowptr);
    hipMemcpyAsync(cursor, rowptr, (size_t)N_NODES * 4, hipMemcpyDeviceToDevice, stream);
    k_scatter8<<<SC_GROUPS * SC_CHUNKS, 256, 0, stream>>>(src, dst, cursor, srcs);

    // casts
    k_castw<<<(5 * 16384 + 255) / 256, 256, 0, stream>>>(W_pre, Wl0, Wr0, Wl1, Wr1, wb);
    k_castx<<<(N_NODES * NF / 4 + 255) / 256, 256, 0, stream>>>(x, xb);

    const int mfma_grid = (N_NODES + 63) / 64;   // 1563
    const int post_grid = (N_NODES + 31) / 32;   // 3125
    const int node_grid = (N_NODES + 3) / 4;     // 25000

    // pre-linear (bf16 h0 + fp8 shadow)
    k_mfma_gemm<0, 0, 1><<<mfma_grid, 256, 0, stream>>>(xb, wb_pre, nullptr, nullptr, b_pre, h0, h0f8, N_NODES);
    // conv0
    k_aggregate8<<<node_grid, 256, 0, stream>>>((const uint2*)h0f8, rowptr, srcs, aggb);
    k_mfma_gemm<1, 1, 1><<<mfma_grid, 256, 0, stream>>>(aggb, wb_l0, h0, wb_r0, bl0, h1, h1f8, N_NODES);
    // conv1
    k_aggregate8<<<node_grid, 256, 0, stream>>>((const uint2*)h1f8, rowptr, srcs, aggb);
    k_mfma_gemm<1, 1, 0><<<mfma_grid, 256, 0, stream>>>(aggb, wb_l1, h1, wb_r1, bl1, h2, nullptr, N_NODES);
    // post + log_softmax
    k_post<<<post_grid, 256, 0, stream>>>(h2, W_post, b_post, outp);
}